// Round 5
// baseline (465.883 us; speedup 1.0000x reference)
//
#include <hip/hip_runtime.h>
#include <math.h>

#define N_NODES 50000
#define N_EDGES 800000
#define G_GRAPHS 64
#define CONV_BLOCKS 2048
#define HPAD 16   // padded h row: one 64B line per node

#define WAVE_SYNC() asm volatile("s_waitcnt lgkmcnt(0)" ::: "memory")
#define RFL(v) __builtin_amdgcn_readfirstlane(v)

// ---- mlp1 (+ workspace zeroing) + fused enc/msg-table setup in block 0 ----
__global__ void k_mlp1(const float* __restrict__ x,
                       const float* __restrict__ w1, const float* __restrict__ b1,
                       const float* __restrict__ w2, const float* __restrict__ b2,
                       float* __restrict__ h,
                       int* __restrict__ cnt,
                       float* __restrict__ bn_part, float* __restrict__ g,
                       const float* __restrict__ edge_emb,
                       const float* __restrict__ enc_w, const float* __restrict__ enc_b,
                       const float* __restrict__ pre_w, float* __restrict__ encm) {
  __shared__ float eo[2][4][10];
  int tid = threadIdx.x;
  int n = blockIdx.x * blockDim.x + tid;
  if (n < 1280) bn_part[n] = 0.f;          // [2][32][20]
  if (n < G_GRAPHS * 10) g[n] = 0.f;
  if (n < N_NODES) {
    cnt[n] = 0;
    float xv[10];
#pragma unroll
    for (int k = 0; k < 10; k++) xv[k] = x[n * 10 + k];
    float hid[5];
#pragma unroll
    for (int j = 0; j < 5; j++) {
      float a = b1[j];
#pragma unroll
      for (int k = 0; k < 10; k++) a += xv[k] * w1[k * 5 + j];
      hid[j] = fmaxf(a, 0.f);
    }
#pragma unroll
    for (int f = 0; f < 10; f++) {
      float a = b2[f];
#pragma unroll
      for (int j = 0; j < 5; j++) a += hid[j] * w2[j * 10 + f];
      h[n * HPAD + f] = a;
    }
  }
  if (blockIdx.x == 0) {
    for (int i = tid; i < 80; i += 256) {
      int l = i / 40; int a = (i / 10) % 4; int k = i % 10;
      float s = enc_b[l * 10 + k];
      for (int j = 0; j < 10; j++) s += edge_emb[a * 10 + j] * enc_w[(l * 10 + j) * 10 + k];
      eo[l][a][k] = s;
    }
    __syncthreads();
    for (int i = tid; i < 400; i += 256) {
      int l = i / 200; int a = (i / 50) % 4; int t = (i / 10) % 5; int f = i % 10;
      float s = 0.f;
      for (int k = 0; k < 10; k++) s += eo[l][a][k] * pre_w[((l * 5 + t) * 30 + 20 + k) * 10 + f];
      encm[i] = s;
    }
  }
}

// ---------------- degree count (4 edges/thread) ----------------
__global__ void k_count(const int* __restrict__ dst, int* __restrict__ cnt) {
  int e0 = (blockIdx.x * blockDim.x + threadIdx.x) * 4;
  if (e0 >= N_EDGES) return;
  int4 d = *(const int4*)&dst[e0];
  atomicAdd(&cnt[d.x], 1);
  atomicAdd(&cnt[d.y], 1);
  atomicAdd(&cnt[d.z], 1);
  atomicAdd(&cnt[d.w], 1);
}

// ---------------- single-block exclusive scan + avg_log; also inits fill=rowptr ----------------
__global__ void k_scan(const int* __restrict__ cnt, int* __restrict__ rowptr,
                       int* __restrict__ fill, float* __restrict__ avg_log) {
  __shared__ int wsum[16];
  __shared__ float wlog[16];
  int tid = threadIdx.x;
  int lane = tid & 63, wid = tid >> 6;
  int carry = 0;
  float logacc = 0.f;
  for (int base = 0; base < N_NODES; base += 4096) {
    int i0 = base + tid * 4;
    int4 v = make_int4(0, 0, 0, 0);
    if (i0 < N_NODES) v = *(const int4*)&cnt[i0];
    float p = (float)(v.x + 1) * (float)(v.y + 1) * (float)(v.z + 1) * (float)(v.w + 1);
    logacc += __logf(p);
    int t4 = v.x + v.y + v.z + v.w;
    int x = t4;
#pragma unroll
    for (int d = 1; d < 64; d <<= 1) {
      int y = __shfl_up(x, d, 64);
      if (lane >= d) x += y;
    }
    if (lane == 63) wsum[wid] = x;
    __syncthreads();
    if (wid == 0) {
      int t = (lane < 16) ? wsum[lane] : 0;
#pragma unroll
      for (int d = 1; d < 16; d <<= 1) {
        int y = __shfl_up(t, d, 64);
        if (lane >= d) t += y;
      }
      if (lane < 16) wsum[lane] = t;
    }
    __syncthreads();
    int wexcl = (wid > 0) ? wsum[wid - 1] : 0;
    int total = wsum[15];
    if (i0 < N_NODES) {
      int e0 = carry + wexcl + x - t4;
      int4 r = make_int4(e0, e0 + v.x, e0 + v.x + v.y, e0 + v.x + v.y + v.z);
      *(int4*)&rowptr[i0] = r;
      *(int4*)&fill[i0] = r;
    }
    carry += total;
    __syncthreads();
  }
  if (tid == 0) rowptr[N_NODES] = carry;
  float r = logacc;
#pragma unroll
  for (int d = 32; d >= 1; d >>= 1) r += __shfl_down(r, d, 64);
  if (lane == 0) wlog[wid] = r;
  __syncthreads();
  if (tid == 0) {
    float s = 0.f;
    for (int w = 0; w < 16; w++) s += wlog[w];
    avg_log[0] = s / (float)N_NODES;
  }
}

// ---------------- scatter edges into CSR (fill pre-seeded with rowptr) ----------------
__global__ void k_scatter(const int* __restrict__ src, const int* __restrict__ dst,
                          const int* __restrict__ attr,
                          int* __restrict__ fill, int* __restrict__ epk) {
  int e0 = (blockIdx.x * blockDim.x + threadIdx.x) * 4;
  if (e0 >= N_EDGES) return;
  int4 s = *(const int4*)&src[e0];
  int4 d = *(const int4*)&dst[e0];
  int4 a = *(const int4*)&attr[e0];
  epk[atomicAdd(&fill[d.x], 1)] = s.x | (a.x << 16);
  epk[atomicAdd(&fill[d.y], 1)] = s.y | (a.y << 16);
  epk[atomicAdd(&fill[d.z], 1)] = s.z | (a.z << 16);
  epk[atomicAdd(&fill[d.w], 1)] = s.w | (a.w << 16);
}

// ---- fused PNA conv: scalar-path gather (uniform src per edge -> s_load), no edge-loop LDS ----
__global__ __launch_bounds__(256) void k_conv(
    const float* __restrict__ h,         // padded [N][16]
    const float* __restrict__ pre_w_l,   // [5][30][10]
    const float* __restrict__ pre_b_l,   // [5][10]
    const float* __restrict__ post_w_l,  // [5][130][2]
    const float* __restrict__ post_b_l,  // [5][2]
    const float* __restrict__ lin_w_l,   // [10][10]
    const float* __restrict__ lin_b_l,   // [10]
    const float* __restrict__ encm_l,    // [4][5][10]
    const int* __restrict__ rowptr,
    const int* __restrict__ epk,
    const float* __restrict__ avg_log_p,
    float* __restrict__ o_buf,
    float* __restrict__ bn_part)         // [32][20]
{
  __shared__ float sW[1300];
  __shared__ float sLin[100];
  __shared__ float sLb[10];
  __shared__ float sPb[10];
  __shared__ float sP[4][100];
  __shared__ float sO[4][10];
  __shared__ float bnS[10], bnQ[10];

  int tid = threadIdx.x;
  int wid = tid >> 6, lane = tid & 63;
  for (int i = tid; i < 1300; i += 256) sW[i] = post_w_l[i];
  for (int i = tid; i < 100; i += 256) sLin[i] = lin_w_l[i];
  if (tid < 10) {
    sLb[tid] = lin_b_l[tid];
    sPb[tid] = post_b_l[tid];
    bnS[tid] = 0.f; bnQ[tid] = 0.f;
  }
  __syncthreads();

  int f = lane % 10;
  int t = (lane < 50) ? (lane / 10) : 4;
  float ws[10], wdst[10];
#pragma unroll
  for (int k = 0; k < 10; k++) {
    ws[k]   = pre_w_l[(t * 30 + 10 + k) * 10 + f];
    wdst[k] = pre_w_l[(t * 30 + k) * 10 + f];
  }
  float em0 = encm_l[t * 10 + f];
  float em1 = encm_l[50 + t * 10 + f];
  float em2 = encm_l[100 + t * 10 + f];
  float em3 = encm_l[150 + t * 10 + f];
  float preb = pre_b_l[t * 10 + f];
  float avg_log = avg_log_p[0];

  int gw = blockIdx.x * 4 + wid;       // global wave id
  int GW = gridDim.x * 4;
  int nn = (gw < N_NODES) ? ((N_NODES - 1 - gw) / GW + 1) : 0;

  // prefetch rowptr pairs for all my nodes (lane-parallel; nn<=7 -> lanes<14 used)
  int rp = 0;
  {
    int i = lane >> 1, which = lane & 1;
    if (i < nn) rp = rowptr[gw + i * GW + which];
  }

  float bnSv = 0.f, bnQv = 0.f;

  for (int i = 0; i < nn; i++) {
    int n = gw + i * GW;
    int rs = RFL(__builtin_amdgcn_readlane(rp, 2 * i));
    int re = RFL(__builtin_amdgcn_readlane(rp, 2 * i + 1));
    int deg = re - rs;

    const float* hn = h + n * HPAD;          // uniform address
    float4 b0 = *(const float4*)hn;
    float4 b1 = *(const float4*)(hn + 4);
    float2 b2 = *(const float2*)(hn + 8);
    float xf = hn[f];                        // per-lane, same 64B line -> broadcast
    float base = preb
      + b0.x * wdst[0] + b0.y * wdst[1] + b0.z * wdst[2] + b0.w * wdst[3]
      + b1.x * wdst[4] + b1.y * wdst[5] + b1.z * wdst[6] + b1.w * wdst[7]
      + b2.x * wdst[8] + b2.y * wdst[9];

    float sum = 0.f, sq = 0.f, mnv = INFINITY, mxv = -INFINITY;
    for (int cs = rs; cs < re; cs += 64) {
      int cdeg = min(64, re - cs);           // scalar
      int pk = (lane < cdeg) ? epk[cs + lane] : 0;
      // prefetch edge 0 (scalar path)
      int pkc = RFL(__builtin_amdgcn_readlane(pk, 0));
      const float* hc = h + (pkc & 0xFFFF) * HPAD;
      float4 c0 = *(const float4*)hc;
      float4 c1 = *(const float4*)(hc + 4);
      float2 c2 = *(const float2*)(hc + 8);
      for (int j = 0; j < cdeg; j++) {
        float4 a0 = c0, a1 = c1; float2 a2 = c2;
        int aj = pkc >> 16;
        if (j + 1 < cdeg) {                  // uniform branch: prefetch next edge
          pkc = RFL(__builtin_amdgcn_readlane(pk, j + 1));
          const float* hx = h + (pkc & 0xFFFF) * HPAD;
          c0 = *(const float4*)hx;
          c1 = *(const float4*)(hx + 4);
          c2 = *(const float2*)(hx + 8);
        }
        float em = (aj & 2) ? ((aj & 1) ? em3 : em2) : ((aj & 1) ? em1 : em0);
        float m = base + em
          + a0.x * ws[0] + a0.y * ws[1] + a0.z * ws[2] + a0.w * ws[3]
          + a1.x * ws[4] + a1.y * ws[5] + a1.z * ws[6] + a1.w * ws[7]
          + a2.x * ws[8] + a2.y * ws[9];
        sum += m; sq = fmaf(m, m, sq);
        mnv = fminf(mnv, m); mxv = fmaxf(mxv, m);
      }
    }

    float degf = (float)deg;
    float d = fmaxf(degf, 1.f);
    float inv = 1.f / d;
    float mean = sum * inv;
    float var = sq * inv - mean * mean;
    float stdv = sqrtf(fmaxf(var, 0.f) + 1e-5f);
    if (deg == 0) { mnv = 0.f; mxv = 0.f; }
    float log_d = logf(d + 1.f);
    float amp = log_d / avg_log;
    float att = avg_log / log_d;

    float vv[13];
    vv[0] = xf;
    vv[1] = mean;       vv[2] = mnv;        vv[3] = mxv;        vv[4] = stdv;
    vv[5] = mean * amp; vv[6] = mnv * amp;  vv[7] = mxv * amp;  vv[8] = stdv * amp;
    vv[9] = mean * att; vv[10] = mnv * att; vv[11] = mxv * att; vv[12] = stdv * att;
    float p0 = 0.f, p1 = 0.f;
#pragma unroll
    for (int j = 0; j < 13; j++) {
      const float2 w = *(const float2*)&sW[t * 260 + (f + 10 * j) * 2];
      p0 += vv[j] * w.x; p1 += vv[j] * w.y;
    }
    if (lane < 50) *(float2*)&sP[wid][(t * 10 + f) * 2] = make_float2(p0, p1);
    WAVE_SYNC();
    if (lane < 10) {
      int tt = lane >> 1, c = lane & 1;
      float o = sPb[lane];
#pragma unroll
      for (int ff = 0; ff < 10; ff++) o += sP[wid][(tt * 10 + ff) * 2 + c];
      sO[wid][lane] = o;
    }
    WAVE_SYNC();
    if (lane < 10) {
      float r = sLb[lane];
#pragma unroll
      for (int j = 0; j < 10; j++) r += sO[wid][j] * sLin[j * 10 + lane];
      o_buf[n * 10 + lane] = r;
      bnSv += r; bnQv += r * r;
    }
    WAVE_SYNC();  // sO/sP reads done before next node reuses them
  }

  if (lane < 10) {
    atomicAdd(&bnS[lane], bnSv);
    atomicAdd(&bnQ[lane], bnQv);
  }
  __syncthreads();
  if (tid < 20) {
    float v = (tid < 10) ? bnS[tid] : bnQ[tid - 10];
    atomicAdd(&bn_part[(blockIdx.x & 31) * 20 + tid], v);
  }
}

// ---------------- BN (train-mode, from 32 partials) + relu + optional pool ----------------
__global__ void k_bnpool(const float* __restrict__ o_buf,
                         const float* __restrict__ bn_part,  // [32][20]
                         const float* __restrict__ gamma, const float* __restrict__ beta,
                         float* __restrict__ h,              // padded [N][16]
                         const int* __restrict__ batch, float* __restrict__ g,
                         int do_pool) {
  __shared__ float sS[20];
  __shared__ float sMu[10], sInv[10];
  int tid = threadIdx.x;
  if (tid < 20) {
    float s = 0.f;
    for (int j = 0; j < 32; j++) s += bn_part[j * 20 + tid];
    sS[tid] = s;
  }
  __syncthreads();
  if (tid < 10) {
    float mu = sS[tid] * (1.f / N_NODES);
    float var = sS[10 + tid] * (1.f / N_NODES) - mu * mu;
    sMu[tid] = mu;
    sInv[tid] = 1.f / sqrtf(fmaxf(var, 0.f) + 1e-5f);
  }
  __syncthreads();
  int i = blockIdx.x * blockDim.x + tid;
  if (i >= N_NODES * 10) return;
  int n = i / 10, f = i % 10;
  float o = (o_buf[i] - sMu[f]) * sInv[f] * gamma[f] + beta[f];
  float r = fmaxf(o, 0.f);
  h[n * HPAD + f] = r;
  if (do_pool) atomicAdd(&g[batch[n] * 10 + f], r);
}

// ---------------- mlp2 ----------------
__global__ void k_mlp2(const float* __restrict__ g,
                       const float* __restrict__ w1, const float* __restrict__ b1,
                       const float* __restrict__ w2, const float* __restrict__ b2,
                       float* __restrict__ out) {
  int b = threadIdx.x;
  if (b >= G_GRAPHS) return;
  float gv[10];
#pragma unroll
  for (int k = 0; k < 10; k++) gv[k] = g[b * 10 + k];
  float acc = b2[0];
#pragma unroll
  for (int j = 0; j < 5; j++) {
    float a = b1[j];
#pragma unroll
    for (int k = 0; k < 10; k++) a += gv[k] * w1[k * 5 + j];
    acc += fmaxf(a, 0.f) * w2[j];
  }
  out[b] = acc;
}

extern "C" void kernel_launch(void* const* d_in, const int* in_sizes, int n_in,
                              void* d_out, int out_size, void* d_ws, size_t ws_size,
                              hipStream_t stream) {
  const float* x        = (const float*)d_in[0];
  const float* edge_emb = (const float*)d_in[1];
  const float* m1w1 = (const float*)d_in[2];
  const float* m1b1 = (const float*)d_in[3];
  const float* m1w2 = (const float*)d_in[4];
  const float* m1b2 = (const float*)d_in[5];
  const float* enc_w = (const float*)d_in[6];
  const float* enc_b = (const float*)d_in[7];
  const float* pre_w = (const float*)d_in[8];
  const float* pre_b = (const float*)d_in[9];
  const float* post_w = (const float*)d_in[10];
  const float* post_b = (const float*)d_in[11];
  const float* lin_w = (const float*)d_in[12];
  const float* lin_b = (const float*)d_in[13];
  const float* bn_g = (const float*)d_in[14];
  const float* bn_b = (const float*)d_in[15];
  const float* m2w1 = (const float*)d_in[16];
  const float* m2b1 = (const float*)d_in[17];
  const float* m2w2 = (const float*)d_in[18];
  const float* m2b2 = (const float*)d_in[19];
  const int* edge_index = (const int*)d_in[20];
  const int* edge_attr  = (const int*)d_in[21];
  const int* batch      = (const int*)d_in[22];
  const int* src  = edge_index;
  const int* dstp = edge_index + N_EDGES;

  char* ws = (char*)d_ws;
  size_t off = 0;
  auto alloc = [&](size_t bytes) {
    void* p = ws + off;
    off += (bytes + 255) & ~(size_t)255;
    return p;
  };
  float* h       = (float*)alloc(N_NODES * HPAD * sizeof(float));
  float* o_buf   = (float*)alloc(N_NODES * 10 * sizeof(float));
  int*   cnt     = (int*)alloc(N_NODES * sizeof(int));
  int*   fill    = (int*)alloc(N_NODES * sizeof(int));
  int*   rowptr  = (int*)alloc((N_NODES + 1) * sizeof(int));
  int*   epk     = (int*)alloc(N_EDGES * sizeof(int));
  float* encm    = (float*)alloc(400 * sizeof(float));
  float* avg_log = (float*)alloc(16);
  float* bn_part = (float*)alloc(2 * 32 * 20 * sizeof(float));
  float* g       = (float*)alloc(G_GRAPHS * 10 * sizeof(float));

  k_mlp1<<<(N_NODES + 255) / 256, 256, 0, stream>>>(x, m1w1, m1b1, m1w2, m1b2, h,
                                                    cnt, bn_part, g,
                                                    edge_emb, enc_w, enc_b, pre_w, encm);
  k_count<<<(N_EDGES / 4 + 255) / 256, 256, 0, stream>>>(dstp, cnt);
  k_scan<<<1, 1024, 0, stream>>>(cnt, rowptr, fill, avg_log);
  k_scatter<<<(N_EDGES / 4 + 255) / 256, 256, 0, stream>>>(src, dstp, edge_attr, fill, epk);

  for (int l = 0; l < 2; l++) {
    k_conv<<<CONV_BLOCKS, 256, 0, stream>>>(
        h, pre_w + l * 1500, pre_b + l * 50, post_w + l * 1300, post_b + l * 10,
        lin_w + l * 100, lin_b + l * 10, encm + l * 200,
        rowptr, epk, avg_log, o_buf, bn_part + l * 640);
    k_bnpool<<<(N_NODES * 10 + 255) / 256, 256, 0, stream>>>(
        o_buf, bn_part + l * 640, bn_g + l * 10, bn_b + l * 10, h, batch, g, l == 1);
  }
  k_mlp2<<<1, 64, 0, stream>>>(g, m2w1, m2b1, m2w2, m2b2, (float*)d_out);
}

// Round 6
// 363.183 us; speedup vs baseline: 1.2828x; 1.2828x over previous
//
#include <hip/hip_runtime.h>
#include <math.h>

#define N_NODES 50000
#define N_EDGES 800000
#define G_GRAPHS 64
#define CONV_BLOCKS 2048

#define WAVE_SYNC() asm volatile("s_waitcnt lgkmcnt(0)" ::: "memory")
#define RFL(v) __builtin_amdgcn_readfirstlane(v)

// ---- mlp1 (+ workspace zeroing) + fused enc/msg-table setup in block 0 ----
__global__ void k_mlp1(const float* __restrict__ x,
                       const float* __restrict__ w1, const float* __restrict__ b1,
                       const float* __restrict__ w2, const float* __restrict__ b2,
                       float* __restrict__ h,
                       int* __restrict__ cnt,
                       float* __restrict__ bn_part, float* __restrict__ g,
                       const float* __restrict__ edge_emb,
                       const float* __restrict__ enc_w, const float* __restrict__ enc_b,
                       const float* __restrict__ pre_w, float* __restrict__ encm) {
  __shared__ float eo[2][4][10];
  int tid = threadIdx.x;
  int n = blockIdx.x * blockDim.x + tid;
  if (n < 1280) bn_part[n] = 0.f;          // [2][32][20]
  if (n < G_GRAPHS * 10) g[n] = 0.f;
  if (n < N_NODES) {
    cnt[n] = 0;
    float xv[10];
#pragma unroll
    for (int k = 0; k < 10; k++) xv[k] = x[n * 10 + k];
    float hid[5];
#pragma unroll
    for (int j = 0; j < 5; j++) {
      float a = b1[j];
#pragma unroll
      for (int k = 0; k < 10; k++) a += xv[k] * w1[k * 5 + j];
      hid[j] = fmaxf(a, 0.f);
    }
#pragma unroll
    for (int f = 0; f < 10; f++) {
      float a = b2[f];
#pragma unroll
      for (int j = 0; j < 5; j++) a += hid[j] * w2[j * 10 + f];
      h[n * 10 + f] = a;
    }
  }
  if (blockIdx.x == 0) {
    for (int i = tid; i < 80; i += 256) {
      int l = i / 40; int a = (i / 10) % 4; int k = i % 10;
      float s = enc_b[l * 10 + k];
      for (int j = 0; j < 10; j++) s += edge_emb[a * 10 + j] * enc_w[(l * 10 + j) * 10 + k];
      eo[l][a][k] = s;
    }
    __syncthreads();
    for (int i = tid; i < 400; i += 256) {
      int l = i / 200; int a = (i / 50) % 4; int t = (i / 10) % 5; int f = i % 10;
      float s = 0.f;
      for (int k = 0; k < 10; k++) s += eo[l][a][k] * pre_w[((l * 5 + t) * 30 + 20 + k) * 10 + f];
      encm[i] = s;
    }
  }
}

// ---------------- degree count (4 edges/thread) ----------------
__global__ void k_count(const int* __restrict__ dst, int* __restrict__ cnt) {
  int e0 = (blockIdx.x * blockDim.x + threadIdx.x) * 4;
  if (e0 >= N_EDGES) return;
  int4 d = *(const int4*)&dst[e0];
  atomicAdd(&cnt[d.x], 1);
  atomicAdd(&cnt[d.y], 1);
  atomicAdd(&cnt[d.z], 1);
  atomicAdd(&cnt[d.w], 1);
}

// ---------------- single-block exclusive scan + avg_log; also inits fill=rowptr ----------------
__global__ void k_scan(const int* __restrict__ cnt, int* __restrict__ rowptr,
                       int* __restrict__ fill, float* __restrict__ avg_log) {
  __shared__ int wsum[16];
  __shared__ float wlog[16];
  int tid = threadIdx.x;
  int lane = tid & 63, wid = tid >> 6;
  int carry = 0;
  float logacc = 0.f;
  for (int base = 0; base < N_NODES; base += 4096) {
    int i0 = base + tid * 4;
    int4 v = make_int4(0, 0, 0, 0);
    if (i0 < N_NODES) v = *(const int4*)&cnt[i0];
    float p = (float)(v.x + 1) * (float)(v.y + 1) * (float)(v.z + 1) * (float)(v.w + 1);
    logacc += __logf(p);
    int t4 = v.x + v.y + v.z + v.w;
    int x = t4;
#pragma unroll
    for (int d = 1; d < 64; d <<= 1) {
      int y = __shfl_up(x, d, 64);
      if (lane >= d) x += y;
    }
    if (lane == 63) wsum[wid] = x;
    __syncthreads();
    if (wid == 0) {
      int t = (lane < 16) ? wsum[lane] : 0;
#pragma unroll
      for (int d = 1; d < 16; d <<= 1) {
        int y = __shfl_up(t, d, 64);
        if (lane >= d) t += y;
      }
      if (lane < 16) wsum[lane] = t;
    }
    __syncthreads();
    int wexcl = (wid > 0) ? wsum[wid - 1] : 0;
    int total = wsum[15];
    if (i0 < N_NODES) {
      int e0 = carry + wexcl + x - t4;
      int4 r = make_int4(e0, e0 + v.x, e0 + v.x + v.y, e0 + v.x + v.y + v.z);
      *(int4*)&rowptr[i0] = r;
      *(int4*)&fill[i0] = r;
    }
    carry += total;
    __syncthreads();
  }
  if (tid == 0) rowptr[N_NODES] = carry;
  float r = logacc;
#pragma unroll
  for (int d = 32; d >= 1; d >>= 1) r += __shfl_down(r, d, 64);
  if (lane == 0) wlog[wid] = r;
  __syncthreads();
  if (tid == 0) {
    float s = 0.f;
    for (int w = 0; w < 16; w++) s += wlog[w];
    avg_log[0] = s / (float)N_NODES;
  }
}

// ---------------- scatter edges into CSR (fill pre-seeded with rowptr) ----------------
__global__ void k_scatter(const int* __restrict__ src, const int* __restrict__ dst,
                          const int* __restrict__ attr,
                          int* __restrict__ fill, int* __restrict__ epk) {
  int e0 = (blockIdx.x * blockDim.x + threadIdx.x) * 4;
  if (e0 >= N_EDGES) return;
  int4 s = *(const int4*)&src[e0];
  int4 d = *(const int4*)&dst[e0];
  int4 a = *(const int4*)&attr[e0];
  epk[atomicAdd(&fill[d.x], 1)] = s.x | (a.x << 16);
  epk[atomicAdd(&fill[d.y], 1)] = s.y | (a.y << 16);
  epk[atomicAdd(&fill[d.z], 1)] = s.z | (a.z << 16);
  epk[atomicAdd(&fill[d.w], 1)] = s.w | (a.w << 16);
}

// ---------------- u[n][t*10+f] = sum_k h[n][k] * pre_w[t][10+k][f] ----------------
__global__ __launch_bounds__(256) void k_u(const float* __restrict__ h,
                                           const float* __restrict__ pre_w_l,
                                           float* __restrict__ u) {
  __shared__ float sw[500];   // [t][k][f]
  int tid = threadIdx.x;
  for (int j = tid; j < 500; j += 256) {
    int t = j / 100, k = (j / 10) % 10, f = j % 10;
    sw[j] = pre_w_l[(t * 30 + 10 + k) * 10 + f];
  }
  __syncthreads();
  int i = blockIdx.x * 256 + tid;
  if (i >= N_NODES * 50) return;
  int n = i / 50, c = i % 50;
  int tb = (c / 10) * 100 + (c % 10);
  const float* hn = h + n * 10;
  float acc = 0.f;
#pragma unroll
  for (int k = 0; k < 10; k++) acc += hn[k] * sw[tb + k * 10];
  u[i] = acc;
}

// ---- fused PNA conv: per-edge = 1 gather of u[src] + em-select + stats. No edge-loop LDS ----
__global__ __launch_bounds__(256) void k_conv(
    const float* __restrict__ h,         // [N][10]
    const float* __restrict__ u,         // [N][50]
    const float* __restrict__ pre_w_l,   // [5][30][10]
    const float* __restrict__ pre_b_l,   // [5][10]
    const float* __restrict__ post_w_l,  // [5][130][2]
    const float* __restrict__ post_b_l,  // [5][2]
    const float* __restrict__ lin_w_l,   // [10][10]
    const float* __restrict__ lin_b_l,   // [10]
    const float* __restrict__ encm_l,    // [4][5][10]
    const int* __restrict__ rowptr,
    const int* __restrict__ epk,
    const float* __restrict__ avg_log_p,
    float* __restrict__ o_buf,
    float* __restrict__ bn_part)         // [32][20]
{
  __shared__ float sW[1300];
  __shared__ float sLin[100];
  __shared__ float sLb[10];
  __shared__ float sPb[10];
  __shared__ float sP[4][100];
  __shared__ float sO[4][10];
  __shared__ float bnS[10], bnQ[10];

  int tid = threadIdx.x;
  int wid = tid >> 6, lane = tid & 63;
  for (int i = tid; i < 1300; i += 256) sW[i] = post_w_l[i];
  for (int i = tid; i < 100; i += 256) sLin[i] = lin_w_l[i];
  if (tid < 10) {
    sLb[tid] = lin_b_l[tid];
    sPb[tid] = post_b_l[tid];
    bnS[tid] = 0.f; bnQ[tid] = 0.f;
  }
  __syncthreads();

  int f = lane % 10;
  int t = (lane < 50) ? (lane / 10) : 4;
  int c50 = t * 10 + f;
  float wdst[10];
#pragma unroll
  for (int k = 0; k < 10; k++) wdst[k] = pre_w_l[(t * 30 + k) * 10 + f];
  float em0 = encm_l[c50];
  float em1 = encm_l[50 + c50];
  float em2 = encm_l[100 + c50];
  float em3 = encm_l[150 + c50];
  float preb = pre_b_l[c50];
  float avg_log = avg_log_p[0];

  int gw = blockIdx.x * 4 + wid;       // global wave id
  int GW = gridDim.x * 4;
  int nn = (gw < N_NODES) ? ((N_NODES - 1 - gw) / GW + 1) : 0;

  int rp = 0;
  {
    int i = lane >> 1, which = lane & 1;
    if (i < nn) rp = rowptr[gw + i * GW + which];
  }

  float bnSv = 0.f, bnQv = 0.f;

#define PRE(US, AS, IDX) { int sp_ = __builtin_amdgcn_readlane(pk, (IDX) & 63); \
    AS = sp_ >> 16; US = 0.f; \
    if ((IDX) < cdeg) US = u[(sp_ & 0xFFFF) * 50 + c50]; }
#define PROC(US, AS) { float em_ = (AS & 2) ? ((AS & 1) ? em3 : em2) : ((AS & 1) ? em1 : em0); \
    float m_ = base + em_ + US; \
    sum += m_; sq = fmaf(m_, m_, sq); mnv = fminf(mnv, m_); mxv = fmaxf(mxv, m_); }

  for (int i = 0; i < nn; i++) {
    int n = gw + i * GW;
    int rs = RFL(__builtin_amdgcn_readlane(rp, 2 * i));
    int re = RFL(__builtin_amdgcn_readlane(rp, 2 * i + 1));
    int deg = re - rs;

    const float* hn = h + n * 10;            // uniform address, 8B-aligned
    float2 d0 = *(const float2*)hn;
    float2 d1 = *(const float2*)(hn + 2);
    float2 d2 = *(const float2*)(hn + 4);
    float2 d3 = *(const float2*)(hn + 6);
    float2 d4 = *(const float2*)(hn + 8);
    float xf = hn[f];
    float base = preb
      + d0.x * wdst[0] + d0.y * wdst[1] + d1.x * wdst[2] + d1.y * wdst[3]
      + d2.x * wdst[4] + d2.y * wdst[5] + d3.x * wdst[6] + d3.y * wdst[7]
      + d4.x * wdst[8] + d4.y * wdst[9];

    float sum = 0.f, sq = 0.f, mnv = INFINITY, mxv = -INFINITY;
    for (int cs = rs; cs < re; cs += 64) {
      int cdeg = min(64, re - cs);           // scalar
      int pk = (lane < cdeg) ? epk[cs + lane] : 0;
      float u0, u1, u2, u3; int a0, a1, a2, a3;
      PRE(u0, a0, 0) PRE(u1, a1, 1) PRE(u2, a2, 2) PRE(u3, a3, 3)
      int full = cdeg & ~3;
      int jb = 0;
      for (; jb < full; jb += 4) {
        PROC(u0, a0) PRE(u0, a0, jb + 4)
        PROC(u1, a1) PRE(u1, a1, jb + 5)
        PROC(u2, a2) PRE(u2, a2, jb + 6)
        PROC(u3, a3) PRE(u3, a3, jb + 7)
      }
      if (jb + 0 < cdeg) PROC(u0, a0)
      if (jb + 1 < cdeg) PROC(u1, a1)
      if (jb + 2 < cdeg) PROC(u2, a2)
    }

    float degf = (float)deg;
    float d = fmaxf(degf, 1.f);
    float inv = 1.f / d;
    float mean = sum * inv;
    float var = sq * inv - mean * mean;
    float stdv = sqrtf(fmaxf(var, 0.f) + 1e-5f);
    if (deg == 0) { mnv = 0.f; mxv = 0.f; }
    float log_d = logf(d + 1.f);
    float amp = log_d / avg_log;
    float att = avg_log / log_d;

    float vv[13];
    vv[0] = xf;
    vv[1] = mean;       vv[2] = mnv;        vv[3] = mxv;        vv[4] = stdv;
    vv[5] = mean * amp; vv[6] = mnv * amp;  vv[7] = mxv * amp;  vv[8] = stdv * amp;
    vv[9] = mean * att; vv[10] = mnv * att; vv[11] = mxv * att; vv[12] = stdv * att;
    float p0 = 0.f, p1 = 0.f;
#pragma unroll
    for (int j = 0; j < 13; j++) {
      const float2 w = *(const float2*)&sW[t * 260 + (f + 10 * j) * 2];
      p0 += vv[j] * w.x; p1 += vv[j] * w.y;
    }
    if (lane < 50) *(float2*)&sP[wid][c50 * 2] = make_float2(p0, p1);
    WAVE_SYNC();
    if (lane < 10) {
      int tt = lane >> 1, c = lane & 1;
      float o = sPb[lane];
#pragma unroll
      for (int ff = 0; ff < 10; ff++) o += sP[wid][(tt * 10 + ff) * 2 + c];
      sO[wid][lane] = o;
    }
    WAVE_SYNC();
    if (lane < 10) {
      float r = sLb[lane];
#pragma unroll
      for (int j = 0; j < 10; j++) r += sO[wid][j] * sLin[j * 10 + lane];
      o_buf[n * 10 + lane] = r;
      bnSv += r; bnQv += r * r;
    }
    WAVE_SYNC();
  }
#undef PRE
#undef PROC

  if (lane < 10) {
    atomicAdd(&bnS[lane], bnSv);
    atomicAdd(&bnQ[lane], bnQv);
  }
  __syncthreads();
  if (tid < 20) {
    float v = (tid < 10) ? bnS[tid] : bnQ[tid - 10];
    atomicAdd(&bn_part[(blockIdx.x & 31) * 20 + tid], v);
  }
}

// ---------------- BN (from 32 partials) + relu + LDS-staged global add pool ----------------
__global__ void k_bnpool(const float* __restrict__ o_buf,
                         const float* __restrict__ bn_part,  // [32][20]
                         const float* __restrict__ gamma, const float* __restrict__ beta,
                         float* __restrict__ h,              // [N][10]
                         const int* __restrict__ batch, float* __restrict__ g,
                         int do_pool) {
  __shared__ float sS[20];
  __shared__ float sMu[10], sInv[10];
  __shared__ float pool[8][10];
  __shared__ int g0s;
  int tid = threadIdx.x;
  if (tid < 20) {
    float s = 0.f;
    for (int j = 0; j < 32; j++) s += bn_part[j * 20 + tid];
    sS[tid] = s;
  }
  if (tid < 80) pool[tid / 10][tid % 10] = 0.f;
  if (tid == 0) {
    int n0 = blockIdx.x * 256 / 10;
    g0s = batch[(n0 < N_NODES) ? n0 : (N_NODES - 1)];
  }
  __syncthreads();
  if (tid < 10) {
    float mu = sS[tid] * (1.f / N_NODES);
    float var = sS[10 + tid] * (1.f / N_NODES) - mu * mu;
    sMu[tid] = mu;
    sInv[tid] = 1.f / sqrtf(fmaxf(var, 0.f) + 1e-5f);
  }
  __syncthreads();
  int i = blockIdx.x * blockDim.x + tid;
  bool act = i < N_NODES * 10;
  if (act) {
    int n = i / 10, f = i % 10;
    float o = (o_buf[i] - sMu[f]) * sInv[f] * gamma[f] + beta[f];
    float r = fmaxf(o, 0.f);
    h[i] = r;
    if (do_pool) {
      int dg = batch[n] - g0s;
      if (dg < 8) atomicAdd(&pool[dg][f], r);
      else atomicAdd(&g[(g0s + dg) * 10 + f], r);
    }
  }
  if (do_pool) {
    __syncthreads();
    if (tid < 80) {
      float v = pool[tid / 10][tid % 10];
      if (v != 0.f) atomicAdd(&g[(g0s + tid / 10) * 10 + tid % 10], v);
    }
  }
}

// ---------------- mlp2 ----------------
__global__ void k_mlp2(const float* __restrict__ g,
                       const float* __restrict__ w1, const float* __restrict__ b1,
                       const float* __restrict__ w2, const float* __restrict__ b2,
                       float* __restrict__ out) {
  int b = threadIdx.x;
  if (b >= G_GRAPHS) return;
  float gv[10];
#pragma unroll
  for (int k = 0; k < 10; k++) gv[k] = g[b * 10 + k];
  float acc = b2[0];
#pragma unroll
  for (int j = 0; j < 5; j++) {
    float a = b1[j];
#pragma unroll
    for (int k = 0; k < 10; k++) a += gv[k] * w1[k * 5 + j];
    acc += fmaxf(a, 0.f) * w2[j];
  }
  out[b] = acc;
}

extern "C" void kernel_launch(void* const* d_in, const int* in_sizes, int n_in,
                              void* d_out, int out_size, void* d_ws, size_t ws_size,
                              hipStream_t stream) {
  const float* x        = (const float*)d_in[0];
  const float* edge_emb = (const float*)d_in[1];
  const float* m1w1 = (const float*)d_in[2];
  const float* m1b1 = (const float*)d_in[3];
  const float* m1w2 = (const float*)d_in[4];
  const float* m1b2 = (const float*)d_in[5];
  const float* enc_w = (const float*)d_in[6];
  const float* enc_b = (const float*)d_in[7];
  const float* pre_w = (const float*)d_in[8];
  const float* pre_b = (const float*)d_in[9];
  const float* post_w = (const float*)d_in[10];
  const float* post_b = (const float*)d_in[11];
  const float* lin_w = (const float*)d_in[12];
  const float* lin_b = (const float*)d_in[13];
  const float* bn_g = (const float*)d_in[14];
  const float* bn_b = (const float*)d_in[15];
  const float* m2w1 = (const float*)d_in[16];
  const float* m2b1 = (const float*)d_in[17];
  const float* m2w2 = (const float*)d_in[18];
  const float* m2b2 = (const float*)d_in[19];
  const int* edge_index = (const int*)d_in[20];
  const int* edge_attr  = (const int*)d_in[21];
  const int* batch      = (const int*)d_in[22];
  const int* src  = edge_index;
  const int* dstp = edge_index + N_EDGES;

  char* ws = (char*)d_ws;
  size_t off = 0;
  auto alloc = [&](size_t bytes) {
    void* p = ws + off;
    off += (bytes + 255) & ~(size_t)255;
    return p;
  };
  float* h       = (float*)alloc(N_NODES * 10 * sizeof(float));
  float* o_buf   = (float*)alloc(N_NODES * 10 * sizeof(float));
  float* u       = (float*)alloc((N_NODES * 50 + 64) * sizeof(float));
  int*   cnt     = (int*)alloc(N_NODES * sizeof(int));
  int*   fill    = (int*)alloc(N_NODES * sizeof(int));
  int*   rowptr  = (int*)alloc((N_NODES + 1) * sizeof(int));
  int*   epk     = (int*)alloc(N_EDGES * sizeof(int));
  float* encm    = (float*)alloc(400 * sizeof(float));
  float* avg_log = (float*)alloc(16);
  float* bn_part = (float*)alloc(2 * 32 * 20 * sizeof(float));
  float* g       = (float*)alloc(G_GRAPHS * 10 * sizeof(float));

  k_mlp1<<<(N_NODES + 255) / 256, 256, 0, stream>>>(x, m1w1, m1b1, m1w2, m1b2, h,
                                                    cnt, bn_part, g,
                                                    edge_emb, enc_w, enc_b, pre_w, encm);
  k_count<<<(N_EDGES / 4 + 255) / 256, 256, 0, stream>>>(dstp, cnt);
  k_scan<<<1, 1024, 0, stream>>>(cnt, rowptr, fill, avg_log);
  k_scatter<<<(N_EDGES / 4 + 255) / 256, 256, 0, stream>>>(src, dstp, edge_attr, fill, epk);

  for (int l = 0; l < 2; l++) {
    k_u<<<(N_NODES * 50 + 255) / 256, 256, 0, stream>>>(h, pre_w + l * 1500, u);
    k_conv<<<CONV_BLOCKS, 256, 0, stream>>>(
        h, u, pre_w + l * 1500, pre_b + l * 50, post_w + l * 1300, post_b + l * 10,
        lin_w + l * 100, lin_b + l * 10, encm + l * 200,
        rowptr, epk, avg_log, o_buf, bn_part + l * 640);
    k_bnpool<<<(N_NODES * 10 + 255) / 256, 256, 0, stream>>>(
        o_buf, bn_part + l * 640, bn_g + l * 10, bn_b + l * 10, h, batch, g, l == 1);
  }
  k_mlp2<<<1, 64, 0, stream>>>(g, m2w1, m2b1, m2w2, m2b2, (float*)d_out);
}